// Round 5
// baseline (251.907 us; speedup 1.0000x reference)
//
#include <hip/hip_runtime.h>

#define B_   4
#define S_   4096
#define NC   8192
#define C_   512
#define CS   256
#define KTOT 768

typedef __attribute__((ext_vector_type(8))) short short8;
typedef __attribute__((ext_vector_type(4))) float f32x4;

// fp32 -> bf16 round-to-nearest-even (finite inputs only)
static __device__ __forceinline__ unsigned short f2bf(float x) {
    unsigned u = __builtin_bit_cast(unsigned, x);
    unsigned r = u + 0x7FFFu + ((u >> 16) & 1u);
    return (unsigned short)(r >> 16);
}

// ================= K1: fused prep =================
// bid 0..63: beff | 64..95: wc | 96..159: w1 | 160..287: pad_ref
// bid 288..1311: seedT transpose (B,256,S) fp32 -> (B,S,256) bf16
__global__ __launch_bounds__(256) void prep_kernel(
        const float* __restrict__ rxyz, float4* __restrict__ refpk,
        const float* __restrict__ Wcat, const float* __restrict__ Wseed,
        unsigned short* __restrict__ Wcomb,
        const float* __restrict__ bseed, const float* __restrict__ bcat,
        float* __restrict__ beff,
        const float* __restrict__ seed, unsigned short* __restrict__ seedT) {
    __shared__ float sa[64][68];
    __shared__ float sbt[64][68];
    int bid = blockIdx.x;
    int tid = threadIdx.x;

    if (bid < 64) {
        int w = tid >> 6, l = tid & 63;
        int o = bid * 4 + w;
        float4 wv = *(const float4*)(Wcat + (size_t)o * 512 + 256 + l * 4);
        float4 bb = *(const float4*)(bseed + l * 4);
        float acc = __fmul_rn(wv.x, bb.x);
        acc = fmaf(wv.y, bb.y, acc);
        acc = fmaf(wv.z, bb.z, acc);
        acc = fmaf(wv.w, bb.w, acc);
        #pragma unroll
        for (int off = 32; off > 0; off >>= 1) acc += __shfl_down(acc, off);
        if (l == 0) beff[o] = acc + bcat[o];
    } else if (bid < 96) {
        int xb = bid - 64;
        int tc = (xb & 7) * 64;
        int to = (xb >> 3) * 64;
        int tx = tid & 15, ty = tid >> 4;
        float acc[4][4] = {};
        for (int kt = 0; kt < 256; kt += 64) {
            __syncthreads();
            #pragma unroll
            for (int r = 0; r < 4; ++r) {
                int oo = r * 16 + ty;
                float4 v = *(const float4*)(Wcat + (size_t)(to + oo) * 512 + 256 + kt + tx * 4);
                sa[oo][tx * 4 + 0] = v.x;
                sa[oo][tx * 4 + 1] = v.y;
                sa[oo][tx * 4 + 2] = v.z;
                sa[oo][tx * 4 + 3] = v.w;
                float4 u = *(const float4*)(Wseed + (size_t)(kt + oo) * 512 + tc + tx * 4);
                sbt[oo][tx * 4 + 0] = u.x;
                sbt[oo][tx * 4 + 1] = u.y;
                sbt[oo][tx * 4 + 2] = u.z;
                sbt[oo][tx * 4 + 3] = u.w;
            }
            __syncthreads();
            for (int k = 0; k < 64; ++k) {
                float a[4], bb2[4];
                #pragma unroll
                for (int i = 0; i < 4; ++i) a[i] = sa[ty * 4 + i][k];
                #pragma unroll
                for (int j = 0; j < 4; ++j) bb2[j] = sbt[k][tx * 4 + j];
                #pragma unroll
                for (int i = 0; i < 4; ++i)
                    #pragma unroll
                    for (int j = 0; j < 4; ++j)
                        acc[i][j] = fmaf(a[i], bb2[j], acc[i][j]);
            }
        }
        #pragma unroll
        for (int i = 0; i < 4; ++i)
            #pragma unroll
            for (int j = 0; j < 4; ++j)
                Wcomb[(size_t)(to + ty * 4 + i) * KTOT + 256 + tc + tx * 4 + j] = f2bf(acc[i][j]);
    } else if (bid < 160) {
        int g = ((bid - 96) * 256 + tid) * 4;
        int o = g >> 8, cc = g & 255;
        float4 v = *(const float4*)(Wcat + (size_t)o * 512 + cc);
        ushort4 ov;
        ov.x = f2bf(v.x); ov.y = f2bf(v.y); ov.z = f2bf(v.z); ov.w = f2bf(v.w);
        *(ushort4*)(Wcomb + (size_t)o * KTOT + cc) = ov;
    } else if (bid < 288) {
        int gid = (bid - 160) * 256 + tid;  // 0..32767
        float x = rxyz[gid * 3 + 0];
        float y = rxyz[gid * 3 + 1];
        float z = rxyz[gid * 3 + 2];
        float r2 = __fadd_rn(__fadd_rn(__fmul_rn(x, x), __fmul_rn(y, y)), __fmul_rn(z, z));
        refpk[gid] = make_float4(x, y, z, r2);
    } else {
        // ---- seedT: transpose+convert seed (B,CS,S) fp32 -> (B,S,CS) bf16 ----
        int id = bid - 288;                // 0..1023
        int b = id >> 8;
        int rem = id & 255;
        int c0 = (rem >> 6) * 64;          // 0..192
        int s0 = (rem & 63) * 64;          // 0..4032
        int tx = tid & 15, ty = tid >> 4;
        #pragma unroll
        for (int r = 0; r < 4; ++r) {
            int cc = r * 16 + ty;
            float4 v = *(const float4*)(seed + ((size_t)b * CS + c0 + cc) * S_ + s0 + tx * 4);
            sa[tx * 4 + 0][cc] = v.x;
            sa[tx * 4 + 1][cc] = v.y;
            sa[tx * 4 + 2][cc] = v.z;
            sa[tx * 4 + 3][cc] = v.w;
        }
        __syncthreads();
        #pragma unroll
        for (int r = 0; r < 4; ++r) {
            int n = r * 16 + ty;
            ushort4 o;
            o.x = f2bf(sa[n][tx * 4 + 0]);
            o.y = f2bf(sa[n][tx * 4 + 1]);
            o.z = f2bf(sa[n][tx * 4 + 2]);
            o.w = f2bf(sa[n][tx * 4 + 3]);
            *(ushort4*)(seedT + ((size_t)b * S_ + s0 + n) * CS + c0 + tx * 4) = o;
        }
    }
}

// ================= K2: fused argmin + transpose + seed-half GEMM =================
// 8192 blocks, bid&3: 0 -> argmin (2048, R3-proven code verbatim),
// 2 -> seed-GEMM (2048: out_partial = Wcomb[:, :256] @ seedT^T, no bias),
// 1/3 -> transpose (4096). Seed-GEMM depends only on prep outputs, so it
// rides mid's idle MFMA pipe + HBM headroom; gemm2 then only does the
// gather half (K=512). LDS overlay stays 16.6 KB -> occupancy unchanged.
__global__ __launch_bounds__(256) void mid_kernel(
        const float* __restrict__ qxyz, const float4* __restrict__ refpk,
        float* __restrict__ pval, int* __restrict__ pidx,
        const float* __restrict__ rf, unsigned short* __restrict__ refT,
        const unsigned short* __restrict__ Wcomb,
        const unsigned short* __restrict__ seedT,
        float* __restrict__ out) {
    // overlay: transpose t[64][65] f32 = 16640 B; sgemm sA[64][72]+sB[32][72] = 13824 B
    __shared__ __align__(16) char smem[16640];
    int bid = blockIdx.x;
    int tid = threadIdx.x;
    int r4 = bid & 3;
    int g = bid >> 2;                      // 0..2047

    if (r4 == 0) {
        // ---------- argmin: one 2048-ref chunk, 32 queries/block (R3 verbatim) ----------
        int aid = g;
        int sblk = aid & 127;
        int c = (aid >> 7) & 3;
        int b = aid >> 9;
        int lane = tid & 63;
        int qg = tid >> 6;
        int sbase = sblk * 32 + qg * 8;

        float qx[8], qy[8], qz[8], q2[8];
        #pragma unroll
        for (int q = 0; q < 8; ++q) {
            const float* qp = qxyz + ((size_t)(b * S_ + sbase + q)) * 3;
            qx[q] = qp[0]; qy[q] = qp[1]; qz[q] = qp[2];
            q2[q] = __fadd_rn(__fadd_rn(__fmul_rn(qx[q], qx[q]), __fmul_rn(qy[q], qy[q])),
                              __fmul_rn(qz[q], qz[q]));
        }

        const float4* ep = refpk + (size_t)b * NC + c * 2048 + lane;
        float best[8];
        int bj[8];
        #pragma unroll
        for (int q = 0; q < 8; ++q) { best[q] = 3.4028235e38f; bj[q] = 0; }

        // 2-deep software prefetch; processing order stays ascending.
        float4 r0 = ep[0];
        float4 r1 = ep[64];
        #pragma unroll 2
        for (int j = 0; j < 32; j += 2) {
            float4 r2 = r0, r3 = r1;
            if (j + 2 < 32) {
                r2 = ep[(j + 2) * 64];
                r3 = ep[(j + 3) * 64];
            }
            #pragma unroll
            for (int q = 0; q < 8; ++q) {
                // qr = ((qx*rx + qy*ry) + qz*rz), no FMA (np association)
                float qr = __fadd_rn(__fadd_rn(__fmul_rn(qx[q], r0.x), __fmul_rn(qy[q], r0.y)),
                                     __fmul_rn(qz[q], r0.z));
                float s = __fadd_rn(q2[q], r0.w);
                float d2 = fmaf(qr, -2.0f, s);   // same single rounding as fsub(s, qr+qr)
                if (d2 < best[q]) { best[q] = d2; bj[q] = j; }
            }
            #pragma unroll
            for (int q = 0; q < 8; ++q) {
                float qr = __fadd_rn(__fadd_rn(__fmul_rn(qx[q], r1.x), __fmul_rn(qy[q], r1.y)),
                                     __fmul_rn(qz[q], r1.z));
                float s = __fadd_rn(q2[q], r1.w);
                float d2 = fmaf(qr, -2.0f, s);
                if (d2 < best[q]) { best[q] = d2; bj[q] = j + 1; }
            }
            r0 = r2;
            r1 = r3;
        }

        int bx[8];
        #pragma unroll
        for (int q = 0; q < 8; ++q) bx[q] = c * 2048 + bj[q] * 64 + lane;

        // In-wave butterfly, (val, idx) lexicographic min = first occurrence.
        #pragma unroll
        for (int m = 1; m < 64; m <<= 1) {
            #pragma unroll
            for (int q = 0; q < 8; ++q) {
                float vv = __shfl_xor(best[q], m, 64);
                int xx = __shfl_xor(bx[q], m, 64);
                if (vv < best[q] || (vv == best[q] && xx < bx[q])) {
                    best[q] = vv; bx[q] = xx;
                }
            }
        }
        if (lane == 0) {
            #pragma unroll
            for (int q = 0; q < 8; ++q) {
                int qs = b * S_ + sbase + q;
                pval[qs * 4 + c] = best[q];
                pidx[qs * 4 + c] = bx[q];
            }
        }
    } else if (r4 == 2) {
        // ---------- seed-half GEMM: 64(M) x 32(N) tile, K=256 ----------
        unsigned short (*sAw)[72] = (unsigned short (*)[72])smem;
        unsigned short (*sBw)[72] = (unsigned short (*)[72])(smem + 9216);
        int b = g >> 9;
        int rem = g & 511;
        int m0 = (rem >> 7) * 64;
        int s0 = (rem & 127) * 32;
        int lane = tid & 63;
        int w = tid >> 6;
        int ln = lane & 15;
        int quad = lane >> 4;
        int q8 = quad * 8;
        int mm = tid >> 2, kk16 = (tid & 3) << 4;
        int n = tid >> 3, kk8 = (tid & 7) << 3;
        const unsigned short* Ar = Wcomb + (size_t)(m0 + mm) * KTOT + kk16;
        const unsigned short* Br = seedT + ((size_t)b * S_ + s0 + n) * CS + kk8;

        f32x4 acc2[2];
        acc2[0] = (f32x4){0.f, 0.f, 0.f, 0.f};
        acc2[1] = (f32x4){0.f, 0.f, 0.f, 0.f};
        for (int kt = 0; kt < 4; ++kt) {
            __syncthreads();
            *(short8*)&sAw[mm][kk16]     = *(const short8*)(Ar + kt * 64);
            *(short8*)&sAw[mm][kk16 + 8] = *(const short8*)(Ar + kt * 64 + 8);
            *(short8*)&sBw[n][kk8]       = *(const short8*)(Br + kt * 64);
            __syncthreads();
            #pragma unroll
            for (int kf = 0; kf < 2; ++kf) {
                short8 af = *(const short8*)&sAw[w * 16 + ln][kf * 32 + q8];
                #pragma unroll
                for (int j = 0; j < 2; ++j) {
                    short8 bfr = *(const short8*)&sBw[j * 16 + ln][kf * 32 + q8];
                    acc2[j] = __builtin_amdgcn_mfma_f32_16x16x32_bf16(af, bfr, acc2[j], 0, 0, 0);
                }
            }
        }
        int mb = m0 + w * 16 + quad * 4;
        #pragma unroll
        for (int j = 0; j < 2; ++j) {
            int col = s0 + j * 16 + ln;
            #pragma unroll
            for (int r = 0; r < 4; ++r)
                out[((size_t)b * CS + mb + r) * S_ + col] = acc2[j][r];  // partial, no bias
        }
    } else {
        // ---------- transpose: (B,C,Nc) fp32 -> (B,Nc,C) bf16 ----------
        float (*t)[65] = (float (*)[65])smem;
        int id = g * 2 + (r4 >> 1);        // r4==1 -> +0, r4==3 -> +1; 0..4095
        int b = id >> 10;
        int c0 = ((id >> 7) & 7) * 64;
        int n0 = (id & 127) * 64;
        int tx = tid & 15, ty = tid >> 4;
        #pragma unroll
        for (int r = 0; r < 4; ++r) {
            int cc = r * 16 + ty;
            float4 v = *(const float4*)(rf + ((size_t)b * C_ + c0 + cc) * NC + n0 + tx * 4);
            t[tx * 4 + 0][cc] = v.x;
            t[tx * 4 + 1][cc] = v.y;
            t[tx * 4 + 2][cc] = v.z;
            t[tx * 4 + 3][cc] = v.w;
        }
        __syncthreads();
        #pragma unroll
        for (int r = 0; r < 4; ++r) {
            int n = r * 16 + ty;
            ushort4 o;
            o.x = f2bf(t[n][tx * 4 + 0]);
            o.y = f2bf(t[n][tx * 4 + 1]);
            o.z = f2bf(t[n][tx * 4 + 2]);
            o.w = f2bf(t[n][tx * 4 + 3]);
            *(ushort4*)(refT + ((size_t)b * NC + n0 + n) * C_ + c0 + tx * 4) = o;
        }
    }
}

// ================= K3: gather-half GEMM (K=256..768), 2-phase pipelined =================
// out += Wcomb[:,256:768] @ gathered refT + bias   (out holds the seed partial)
__global__ __launch_bounds__(256) void fused_gemm_kernel(
        const unsigned short* __restrict__ Wcomb,
        const unsigned short* __restrict__ refT,
        const float* __restrict__ pval,
        const int* __restrict__ pidx,
        const float* __restrict__ beff,
        float* __restrict__ out) {
    __shared__ __align__(16) unsigned short sA[2][128][72];
    __shared__ __align__(16) unsigned short sB[2][32][72];
    __shared__ int sIdx[32];
    __shared__ float sBias[128];

    int tid = threadIdx.x;
    int b = blockIdx.z;
    int m0 = blockIdx.y * 128;
    int s0 = blockIdx.x * 32;
    if (tid < 32) {
        // merge 4 chunk-partials; disjoint ascending index ranges -> (val,idx) min
        int qs = b * S_ + s0 + tid;
        float v = pval[qs * 4 + 0];
        int x = pidx[qs * 4 + 0];
        #pragma unroll
        for (int c = 1; c < 4; ++c) {
            float vv = pval[qs * 4 + c];
            int xx = pidx[qs * 4 + c];
            if (vv < v || (vv == v && xx < x)) { v = vv; x = xx; }
        }
        sIdx[tid] = x & (NC - 1);   // defensive clamp
    }
    if (tid < 128) sBias[tid] = beff[m0 + tid];

    int lane = tid & 63;
    int w = tid >> 6;
    int ln = lane & 15;
    int quad = lane >> 4;
    int q8 = quad * 8;

    int mmb  = tid >> 3;
    int kk8a = (tid & 7) << 3;
    const unsigned short* Arow = Wcomb + (size_t)(m0 + mmb) * KTOT + 256 + kk8a;
    int n_g  = tid >> 3;

    f32x4 acc[2][2];
    #pragma unroll
    for (int i = 0; i < 2; ++i)
        #pragma unroll
        for (int j = 0; j < 2; ++j)
            acc[i][j] = (f32x4){0.f, 0.f, 0.f, 0.f};

    short8 ra[4];
    short8 rb;

    #define SLOAD(PK) do {                                                         \
        int pk0 = (PK) * 64;                                                       \
        _Pragma("unroll")                                                          \
        for (int i = 0; i < 4; ++i)                                                \
            ra[i] = *(const short8*)(Arow + (size_t)i * 32 * KTOT + pk0);          \
        rb = *(const short8*)(refT + ((size_t)b * NC + sIdx[n_g]) * C_             \
                              + pk0 + kk8a);                                       \
    } while (0)

    #define SWRITE(BUF) do {                                                       \
        _Pragma("unroll")                                                          \
        for (int i = 0; i < 4; ++i)                                                \
            *(short8*)&sA[BUF][mmb + 32 * i][kk8a] = ra[i];                        \
        *(short8*)&sB[BUF][n_g][kk8a] = rb;                                        \
    } while (0)

    // NOTE: SLOAD(0) reads sIdx -> needs the barrier AFTER sIdx is written.
    __syncthreads();
    SLOAD(0);
    SWRITE(0);
    __syncthreads();

    int cur = 0;
    for (int ks = 0; ks < 8; ++ks) {
        if (ks < 7) SLOAD(ks + 1);
        #pragma unroll
        for (int kf = 0; kf < 2; ++kf) {
            short8 af[2], bfr[2];
            #pragma unroll
            for (int i = 0; i < 2; ++i)
                af[i] = *(const short8*)&sA[cur][w * 32 + i * 16 + ln][kf * 32 + q8];
            #pragma unroll
            for (int j = 0; j < 2; ++j)
                bfr[j] = *(const short8*)&sB[cur][j * 16 + ln][kf * 32 + q8];
            #pragma unroll
            for (int i = 0; i < 2; ++i)
                #pragma unroll
                for (int j = 0; j < 2; ++j)
                    acc[i][j] = __builtin_amdgcn_mfma_f32_16x16x32_bf16(af[i], bfr[j], acc[i][j], 0, 0, 0);
        }
        if (ks < 7) {
            SWRITE(cur ^ 1);
            __syncthreads();
            cur ^= 1;
        }
    }
    #undef SLOAD
    #undef SWRITE

    #pragma unroll
    for (int i = 0; i < 2; ++i) {
        int mb = w * 32 + i * 16 + quad * 4;
        #pragma unroll
        for (int j = 0; j < 2; ++j) {
            int col = s0 + j * 16 + ln;
            #pragma unroll
            for (int r = 0; r < 4; ++r) {
                int m = mb + r;
                size_t oaddr = ((size_t)b * CS + m0 + m) * S_ + col;
                out[oaddr] = acc[i][j][r] + sBias[m] + out[oaddr];  // + seed partial
            }
        }
    }
}

extern "C" void kernel_launch(void* const* d_in, const int* in_sizes, int n_in,
                              void* d_out, int out_size, void* d_ws, size_t ws_size,
                              hipStream_t stream) {
    const float* qxyz  = (const float*)d_in[0];
    const float* rxyz  = (const float*)d_in[1];
    const float* rfeat = (const float*)d_in[2];
    const float* seed  = (const float*)d_in[3];
    const float* Wseed = (const float*)d_in[4];
    const float* bseed = (const float*)d_in[5];
    const float* Wcat  = (const float*)d_in[6];
    const float* bcat  = (const float*)d_in[7];
    float* out = (float*)d_out;

    char* ws = (char*)d_ws;
    float* pval           = (float*)(ws);                        // 256 KB
    int* pidx             = (int*)(ws + 262144);                 // 256 KB
    float* beff           = (float*)(ws + 524288);               // 1 KB
    float4* refpk         = (float4*)(ws + 528384);              // 512 KB
    unsigned short* Wcomb = (unsigned short*)(ws + 1052672);     // 384 KB
    unsigned short* refT  = (unsigned short*)(ws + 1445888);     // 32 MB
    unsigned short* seedT = (unsigned short*)(ws + 35000320);    // 8 MB -> end 43.4 MB

    hipLaunchKernelGGL(prep_kernel, dim3(1312), dim3(256), 0, stream,
                       rxyz, refpk, Wcat, Wseed, Wcomb, bseed, bcat, beff, seed, seedT);
    hipLaunchKernelGGL(mid_kernel, dim3(8192), dim3(256), 0, stream,
                       qxyz, refpk, pval, pidx, rfeat, refT, Wcomb, seedT, out);
    hipLaunchKernelGGL(fused_gemm_kernel, dim3(128, 2, 4), dim3(256), 0, stream,
                       Wcomb, refT, pval, pidx, beff, out);
}

// Round 6
// 195.893 us; speedup vs baseline: 1.2859x; 1.2859x over previous
//
#include <hip/hip_runtime.h>

#define B_   4
#define S_   4096
#define NC   8192
#define C_   512
#define CS   256
#define KTOT 768

typedef __attribute__((ext_vector_type(8))) short short8;
typedef __attribute__((ext_vector_type(4))) float f32x4;

// fp32 -> bf16 round-to-nearest-even (finite inputs only)
static __device__ __forceinline__ unsigned short f2bf(float x) {
    unsigned u = __builtin_bit_cast(unsigned, x);
    unsigned r = u + 0x7FFFu + ((u >> 16) & 1u);
    return (unsigned short)(r >> 16);
}

// ================= K1: fused prep (R3 verbatim) =================
// bid 0..63: beff | 64..95: wc | 96..159: w1 | 160..287: pad_ref
__global__ __launch_bounds__(256) void prep_kernel(
        const float* __restrict__ rxyz, float4* __restrict__ refpk,
        const float* __restrict__ Wcat, const float* __restrict__ Wseed,
        unsigned short* __restrict__ Wcomb,
        const float* __restrict__ bseed, const float* __restrict__ bcat,
        float* __restrict__ beff) {
    __shared__ float sa[64][68];
    __shared__ float sbt[64][68];
    int bid = blockIdx.x;
    int tid = threadIdx.x;

    if (bid < 64) {
        int w = tid >> 6, l = tid & 63;
        int o = bid * 4 + w;
        float4 wv = *(const float4*)(Wcat + (size_t)o * 512 + 256 + l * 4);
        float4 bb = *(const float4*)(bseed + l * 4);
        float acc = __fmul_rn(wv.x, bb.x);
        acc = fmaf(wv.y, bb.y, acc);
        acc = fmaf(wv.z, bb.z, acc);
        acc = fmaf(wv.w, bb.w, acc);
        #pragma unroll
        for (int off = 32; off > 0; off >>= 1) acc += __shfl_down(acc, off);
        if (l == 0) beff[o] = acc + bcat[o];
    } else if (bid < 96) {
        int xb = bid - 64;
        int tc = (xb & 7) * 64;
        int to = (xb >> 3) * 64;
        int tx = tid & 15, ty = tid >> 4;
        float acc[4][4] = {};
        for (int kt = 0; kt < 256; kt += 64) {
            __syncthreads();
            #pragma unroll
            for (int r = 0; r < 4; ++r) {
                int oo = r * 16 + ty;
                float4 v = *(const float4*)(Wcat + (size_t)(to + oo) * 512 + 256 + kt + tx * 4);
                sa[oo][tx * 4 + 0] = v.x;
                sa[oo][tx * 4 + 1] = v.y;
                sa[oo][tx * 4 + 2] = v.z;
                sa[oo][tx * 4 + 3] = v.w;
                float4 u = *(const float4*)(Wseed + (size_t)(kt + oo) * 512 + tc + tx * 4);
                sbt[oo][tx * 4 + 0] = u.x;
                sbt[oo][tx * 4 + 1] = u.y;
                sbt[oo][tx * 4 + 2] = u.z;
                sbt[oo][tx * 4 + 3] = u.w;
            }
            __syncthreads();
            for (int k = 0; k < 64; ++k) {
                float a[4], bb2[4];
                #pragma unroll
                for (int i = 0; i < 4; ++i) a[i] = sa[ty * 4 + i][k];
                #pragma unroll
                for (int j = 0; j < 4; ++j) bb2[j] = sbt[k][tx * 4 + j];
                #pragma unroll
                for (int i = 0; i < 4; ++i)
                    #pragma unroll
                    for (int j = 0; j < 4; ++j)
                        acc[i][j] = fmaf(a[i], bb2[j], acc[i][j]);
            }
        }
        #pragma unroll
        for (int i = 0; i < 4; ++i)
            #pragma unroll
            for (int j = 0; j < 4; ++j)
                Wcomb[(size_t)(to + ty * 4 + i) * KTOT + 256 + tc + tx * 4 + j] = f2bf(acc[i][j]);
    } else if (bid < 160) {
        int g = ((bid - 96) * 256 + tid) * 4;
        int o = g >> 8, cc = g & 255;
        float4 v = *(const float4*)(Wcat + (size_t)o * 512 + cc);
        ushort4 ov;
        ov.x = f2bf(v.x); ov.y = f2bf(v.y); ov.z = f2bf(v.z); ov.w = f2bf(v.w);
        *(ushort4*)(Wcomb + (size_t)o * KTOT + cc) = ov;
    } else {
        int gid = (bid - 160) * 256 + tid;  // 0..32767
        float x = rxyz[gid * 3 + 0];
        float y = rxyz[gid * 3 + 1];
        float z = rxyz[gid * 3 + 2];
        float r2 = __fadd_rn(__fadd_rn(__fmul_rn(x, x), __fmul_rn(y, y)), __fmul_rn(z, z));
        refpk[gid] = make_float4(x, y, z, r2);
    }
}

// ================= K2: fused argmin + transpose (R3 verbatim, proven 56.5us) =================
// 6144 blocks, 1:2 argmin:transpose interleave.
__global__ __launch_bounds__(256, 4) void mid_kernel(
        const float* __restrict__ qxyz, const float4* __restrict__ refpk,
        float* __restrict__ pval, int* __restrict__ pidx,
        const float* __restrict__ rf, unsigned short* __restrict__ refT) {
    __shared__ float t[64][65];
    int bid = blockIdx.x;
    int tid = threadIdx.x;

    if (bid % 3 != 0) {
        // ---------- transpose path: (B,C,Nc) fp32 -> (B,Nc,C) bf16 ----------
        int id = bid - bid / 3 - 1;        // 0..4095
        int b = id >> 10;
        int c0 = ((id >> 7) & 7) * 64;
        int n0 = (id & 127) * 64;
        int tx = tid & 15, ty = tid >> 4;
        #pragma unroll
        for (int r = 0; r < 4; ++r) {
            int cc = r * 16 + ty;
            float4 v = *(const float4*)(rf + ((size_t)b * C_ + c0 + cc) * NC + n0 + tx * 4);
            t[tx * 4 + 0][cc] = v.x;
            t[tx * 4 + 1][cc] = v.y;
            t[tx * 4 + 2][cc] = v.z;
            t[tx * 4 + 3][cc] = v.w;
        }
        __syncthreads();
        #pragma unroll
        for (int r = 0; r < 4; ++r) {
            int n = r * 16 + ty;
            ushort4 o;
            o.x = f2bf(t[n][tx * 4 + 0]);
            o.y = f2bf(t[n][tx * 4 + 1]);
            o.z = f2bf(t[n][tx * 4 + 2]);
            o.w = f2bf(t[n][tx * 4 + 3]);
            *(ushort4*)(refT + ((size_t)b * NC + n0 + n) * C_ + c0 + tx * 4) = o;
        }
    } else {
        // ---------- argmin path: one 2048-ref chunk, 32 queries/block ----------
        int aid = bid / 3;                 // 0..2047
        int sblk = aid & 127;
        int c = (aid >> 7) & 3;
        int b = aid >> 9;
        int lane = tid & 63;
        int qg = tid >> 6;
        int sbase = sblk * 32 + qg * 8;

        float qx[8], qy[8], qz[8], q2[8];
        #pragma unroll
        for (int q = 0; q < 8; ++q) {
            const float* qp = qxyz + ((size_t)(b * S_ + sbase + q)) * 3;
            qx[q] = qp[0]; qy[q] = qp[1]; qz[q] = qp[2];
            q2[q] = __fadd_rn(__fadd_rn(__fmul_rn(qx[q], qx[q]), __fmul_rn(qy[q], qy[q])),
                              __fmul_rn(qz[q], qz[q]));
        }

        const float4* ep = refpk + (size_t)b * NC + c * 2048 + lane;
        float best[8];
        int bj[8];
        #pragma unroll
        for (int q = 0; q < 8; ++q) { best[q] = 3.4028235e38f; bj[q] = 0; }

        // 2-deep software prefetch; processing order stays ascending.
        float4 r0 = ep[0];
        float4 r1 = ep[64];
        #pragma unroll 2
        for (int j = 0; j < 32; j += 2) {
            float4 r2 = r0, r3 = r1;
            if (j + 2 < 32) {
                r2 = ep[(j + 2) * 64];
                r3 = ep[(j + 3) * 64];
            }
            #pragma unroll
            for (int q = 0; q < 8; ++q) {
                // qr = ((qx*rx + qy*ry) + qz*rz), no FMA (np association)
                float qr = __fadd_rn(__fadd_rn(__fmul_rn(qx[q], r0.x), __fmul_rn(qy[q], r0.y)),
                                     __fmul_rn(qz[q], r0.z));
                float s = __fadd_rn(q2[q], r0.w);
                float d2 = fmaf(qr, -2.0f, s);   // same single rounding as fsub(s, qr+qr)
                if (d2 < best[q]) { best[q] = d2; bj[q] = j; }
            }
            #pragma unroll
            for (int q = 0; q < 8; ++q) {
                float qr = __fadd_rn(__fadd_rn(__fmul_rn(qx[q], r1.x), __fmul_rn(qy[q], r1.y)),
                                     __fmul_rn(qz[q], r1.z));
                float s = __fadd_rn(q2[q], r1.w);
                float d2 = fmaf(qr, -2.0f, s);
                if (d2 < best[q]) { best[q] = d2; bj[q] = j + 1; }
            }
            r0 = r2;
            r1 = r3;
        }

        int bx[8];
        #pragma unroll
        for (int q = 0; q < 8; ++q) bx[q] = c * 2048 + bj[q] * 64 + lane;

        // In-wave butterfly, (val, idx) lexicographic min = first occurrence.
        #pragma unroll
        for (int m = 1; m < 64; m <<= 1) {
            #pragma unroll
            for (int q = 0; q < 8; ++q) {
                float vv = __shfl_xor(best[q], m, 64);
                int xx = __shfl_xor(bx[q], m, 64);
                if (vv < best[q] || (vv == best[q] && xx < bx[q])) {
                    best[q] = vv; bx[q] = xx;
                }
            }
        }
        if (lane == 0) {
            #pragma unroll
            for (int q = 0; q < 8; ++q) {
                int qs = b * S_ + sbase + q;
                pval[qs * 4 + c] = best[q];
                pidx[qs * 4 + c] = bx[q];
            }
        }
    }
}

// ================= K2.5: merge partials + dense row gather =================
// XG[b][s][:] = refT[b][argmin_idx(b,s)][:]  (bf16 rows copied verbatim).
// Moves the random-row access off gemm's per-K-step critical path: each
// winning 1KB row is fetched ONCE, contiguously; gemm then streams XG.
// Merge logic identical to R3's gemm head (disjoint ascending ranges ->
// (val,idx) lexicographic min).
__global__ __launch_bounds__(256) void gather_kernel(
        const unsigned short* __restrict__ refT,
        const float* __restrict__ pval, const int* __restrict__ pidx,
        unsigned short* __restrict__ XG) {
    __shared__ int sIdx[32];
    int tid = threadIdx.x;
    int bid = blockIdx.x;          // 512 blocks
    int b  = bid >> 7;
    int s0 = (bid & 127) * 32;
    if (tid < 32) {
        int qs = b * S_ + s0 + tid;
        float v = pval[qs * 4 + 0];
        int x = pidx[qs * 4 + 0];
        #pragma unroll
        for (int c = 1; c < 4; ++c) {
            float vv = pval[qs * 4 + c];
            int xx = pidx[qs * 4 + c];
            if (vv < v || (vv == v && xx < x)) { v = vv; x = xx; }
        }
        sIdx[tid] = x & (NC - 1);   // defensive clamp
    }
    __syncthreads();
    int r  = tid >> 3;             // row 0..31
    int c0 = (tid & 7) << 3;       // elem offset, 8 threads x 16B = 128B/pass
    const unsigned short* src = refT + ((size_t)b * NC + sIdx[r]) * C_ + c0;
    unsigned short* dst = XG + ((size_t)(b * S_ + s0 + r)) * C_ + c0;
    short8 g[8];
    #pragma unroll
    for (int p = 0; p < 8; ++p) g[p] = *(const short8*)(src + p * 64);
    #pragma unroll
    for (int p = 0; p < 8; ++p) *(short8*)(dst + p * 64) = g[p];
}

// ================= K3: fused GEMM, 2-phase pipelined, dense-B =================
// out[b](256 x 4096) = Wcomb(256x768) @ [seed; XG](768x4096) + b_eff
// Gather half now reads dense XG rows (coalesced, streaming) -> depth-1
// prefetch covers it. No sIdx merge head. MFMA order identical to R3 ->
// bit-identical output.
__global__ __launch_bounds__(256) void fused_gemm_kernel(
        const unsigned short* __restrict__ Wcomb,
        const float* __restrict__ seed,
        const unsigned short* __restrict__ XG,
        const float* __restrict__ beff,
        float* __restrict__ out) {
    __shared__ __align__(16) unsigned short sA[2][128][72];
    __shared__ __align__(16) unsigned short sB[2][32][72];
    __shared__ float sBias[128];

    int tid = threadIdx.x;
    int b = blockIdx.z;
    int m0 = blockIdx.y * 128;
    int s0 = blockIdx.x * 32;
    if (tid < 128) sBias[tid] = beff[m0 + tid];

    int lane = tid & 63;
    int w = tid >> 6;
    int ln = lane & 15;
    int quad = lane >> 4;
    int q8 = quad * 8;

    int mmb  = tid >> 3;
    int kk8a = (tid & 7) << 3;
    const unsigned short* Arow = Wcomb + (size_t)(m0 + mmb) * KTOT + kk8a;
    int n_s  = tid & 31;
    int kk8s = (tid >> 5) << 3;
    int n_g  = tid >> 3;
    const unsigned short* Grow = XG + ((size_t)b * S_ + s0 + n_g) * C_ + kk8a;

    f32x4 acc[2][2];
    #pragma unroll
    for (int i = 0; i < 2; ++i)
        #pragma unroll
        for (int j = 0; j < 2; ++j)
            acc[i][j] = (f32x4){0.f, 0.f, 0.f, 0.f};

    short8 ra[4];
    short8 rb;
    float rbf[8];

    #define SLOAD(PK) do {                                                         \
        int pk0 = (PK) * 64;                                                       \
        _Pragma("unroll")                                                          \
        for (int i = 0; i < 4; ++i)                                                \
            ra[i] = *(const short8*)(Arow + (size_t)i * 32 * KTOT + pk0);          \
        if (pk0 < 256) {                                                           \
            const float* sp = seed + ((size_t)b * CS + pk0 + kk8s) * S_ + s0 + n_s;\
            _Pragma("unroll")                                                      \
            for (int r = 0; r < 8; ++r) rbf[r] = sp[(size_t)r * S_];               \
        } else {                                                                   \
            rb = *(const short8*)(Grow + (pk0 - 256));                             \
        }                                                                          \
    } while (0)

    #define SWRITE(BUF, PK) do {                                                   \
        int pk0 = (PK) * 64;                                                       \
        _Pragma("unroll")                                                          \
        for (int i = 0; i < 4; ++i)                                                \
            *(short8*)&sA[BUF][mmb + 32 * i][kk8a] = ra[i];                        \
        if (pk0 < 256) {                                                           \
            unsigned short tmp[8];                                                 \
            _Pragma("unroll")                                                      \
            for (int r = 0; r < 8; ++r) tmp[r] = f2bf(rbf[r]);                     \
            *(short8*)&sB[BUF][n_s][kk8s] = *(const short8*)tmp;                   \
        } else {                                                                   \
            *(short8*)&sB[BUF][n_g][kk8a] = rb;                                    \
        }                                                                          \
    } while (0)

    SLOAD(0);
    SWRITE(0, 0);
    __syncthreads();

    int cur = 0;
    for (int ks = 0; ks < 12; ++ks) {
        if (ks < 11) SLOAD(ks + 1);
        #pragma unroll
        for (int kf = 0; kf < 2; ++kf) {
            short8 af[2], bfr[2];
            #pragma unroll
            for (int i = 0; i < 2; ++i)
                af[i] = *(const short8*)&sA[cur][w * 32 + i * 16 + ln][kf * 32 + q8];
            #pragma unroll
            for (int j = 0; j < 2; ++j)
                bfr[j] = *(const short8*)&sB[cur][j * 16 + ln][kf * 32 + q8];
            #pragma unroll
            for (int i = 0; i < 2; ++i)
                #pragma unroll
                for (int j = 0; j < 2; ++j)
                    acc[i][j] = __builtin_amdgcn_mfma_f32_16x16x32_bf16(af[i], bfr[j], acc[i][j], 0, 0, 0);
        }
        if (ks < 11) {
            SWRITE(cur ^ 1, ks + 1);
            __syncthreads();
            cur ^= 1;
        }
    }
    #undef SLOAD
    #undef SWRITE

    #pragma unroll
    for (int i = 0; i < 2; ++i) {
        int mb = w * 32 + i * 16 + quad * 4;
        #pragma unroll
        for (int j = 0; j < 2; ++j) {
            int col = s0 + j * 16 + ln;
            #pragma unroll
            for (int r = 0; r < 4; ++r) {
                int m = mb + r;
                out[((size_t)b * CS + m0 + m) * S_ + col] = acc[i][j][r] + sBias[m];
            }
        }
    }
}

extern "C" void kernel_launch(void* const* d_in, const int* in_sizes, int n_in,
                              void* d_out, int out_size, void* d_ws, size_t ws_size,
                              hipStream_t stream) {
    const float* qxyz  = (const float*)d_in[0];
    const float* rxyz  = (const float*)d_in[1];
    const float* rfeat = (const float*)d_in[2];
    const float* seed  = (const float*)d_in[3];
    const float* Wseed = (const float*)d_in[4];
    const float* bseed = (const float*)d_in[5];
    const float* Wcat  = (const float*)d_in[6];
    const float* bcat  = (const float*)d_in[7];
    float* out = (float*)d_out;

    char* ws = (char*)d_ws;
    float* pval           = (float*)(ws);                        // 256 KB
    int* pidx             = (int*)(ws + 262144);                 // 256 KB
    float* beff           = (float*)(ws + 524288);               // 1 KB
    float4* refpk         = (float4*)(ws + 528384);              // 512 KB
    unsigned short* Wcomb = (unsigned short*)(ws + 1052672);     // 384 KB
    unsigned short* refT  = (unsigned short*)(ws + 1445888);     // 32 MB
    unsigned short* XG    = (unsigned short*)(ws + 35000320);    // 16 MB -> end 51.8 MB

    hipLaunchKernelGGL(prep_kernel, dim3(288), dim3(256), 0, stream,
                       rxyz, refpk, Wcat, Wseed, Wcomb, bseed, bcat, beff);
    hipLaunchKernelGGL(mid_kernel, dim3(6144), dim3(256), 0, stream,
                       qxyz, refpk, pval, pidx, rfeat, refT);
    hipLaunchKernelGGL(gather_kernel, dim3(512), dim3(256), 0, stream,
                       refT, pval, pidx, XG);
    hipLaunchKernelGGL(fused_gemm_kernel, dim3(128, 2, 4), dim3(256), 0, stream,
                       Wcomb, seed, XG, beff, out);
}

// Round 7
// 183.294 us; speedup vs baseline: 1.3743x; 1.0687x over previous
//
#include <hip/hip_runtime.h>

#define B_   4
#define S_   4096
#define NC   8192
#define C_   512
#define CS   256
#define KTOT 768

typedef __attribute__((ext_vector_type(8))) short short8;
typedef __attribute__((ext_vector_type(4))) float f32x4;

// fp32 -> bf16 round-to-nearest-even (finite inputs only)
static __device__ __forceinline__ unsigned short f2bf(float x) {
    unsigned u = __builtin_bit_cast(unsigned, x);
    unsigned r = u + 0x7FFFu + ((u >> 16) & 1u);
    return (unsigned short)(r >> 16);
}

// ================= K1: fused prep =================
// bid 0..63: beff | 64..95: wc | 96..159: w1 | 160..287: pad_ref
// bid 288..1311: seedT transpose (B,256,S) fp32 -> (B,S,256) bf16
__global__ __launch_bounds__(256) void prep_kernel(
        const float* __restrict__ rxyz, float4* __restrict__ refpk,
        const float* __restrict__ Wcat, const float* __restrict__ Wseed,
        unsigned short* __restrict__ Wcomb,
        const float* __restrict__ bseed, const float* __restrict__ bcat,
        float* __restrict__ beff,
        const float* __restrict__ seed, unsigned short* __restrict__ seedT) {
    __shared__ float sa[64][68];
    __shared__ float sbt[64][68];
    int bid = blockIdx.x;
    int tid = threadIdx.x;

    if (bid < 64) {
        int w = tid >> 6, l = tid & 63;
        int o = bid * 4 + w;
        float4 wv = *(const float4*)(Wcat + (size_t)o * 512 + 256 + l * 4);
        float4 bb = *(const float4*)(bseed + l * 4);
        float acc = __fmul_rn(wv.x, bb.x);
        acc = fmaf(wv.y, bb.y, acc);
        acc = fmaf(wv.z, bb.z, acc);
        acc = fmaf(wv.w, bb.w, acc);
        #pragma unroll
        for (int off = 32; off > 0; off >>= 1) acc += __shfl_down(acc, off);
        if (l == 0) beff[o] = acc + bcat[o];
    } else if (bid < 96) {
        int xb = bid - 64;
        int tc = (xb & 7) * 64;
        int to = (xb >> 3) * 64;
        int tx = tid & 15, ty = tid >> 4;
        float acc[4][4] = {};
        for (int kt = 0; kt < 256; kt += 64) {
            __syncthreads();
            #pragma unroll
            for (int r = 0; r < 4; ++r) {
                int oo = r * 16 + ty;
                float4 v = *(const float4*)(Wcat + (size_t)(to + oo) * 512 + 256 + kt + tx * 4);
                sa[oo][tx * 4 + 0] = v.x;
                sa[oo][tx * 4 + 1] = v.y;
                sa[oo][tx * 4 + 2] = v.z;
                sa[oo][tx * 4 + 3] = v.w;
                float4 u = *(const float4*)(Wseed + (size_t)(kt + oo) * 512 + tc + tx * 4);
                sbt[oo][tx * 4 + 0] = u.x;
                sbt[oo][tx * 4 + 1] = u.y;
                sbt[oo][tx * 4 + 2] = u.z;
                sbt[oo][tx * 4 + 3] = u.w;
            }
            __syncthreads();
            for (int k = 0; k < 64; ++k) {
                float a[4], bb2[4];
                #pragma unroll
                for (int i = 0; i < 4; ++i) a[i] = sa[ty * 4 + i][k];
                #pragma unroll
                for (int j = 0; j < 4; ++j) bb2[j] = sbt[k][tx * 4 + j];
                #pragma unroll
                for (int i = 0; i < 4; ++i)
                    #pragma unroll
                    for (int j = 0; j < 4; ++j)
                        acc[i][j] = fmaf(a[i], bb2[j], acc[i][j]);
            }
        }
        #pragma unroll
        for (int i = 0; i < 4; ++i)
            #pragma unroll
            for (int j = 0; j < 4; ++j)
                Wcomb[(size_t)(to + ty * 4 + i) * KTOT + 256 + tc + tx * 4 + j] = f2bf(acc[i][j]);
    } else if (bid < 160) {
        int g = ((bid - 96) * 256 + tid) * 4;
        int o = g >> 8, cc = g & 255;
        float4 v = *(const float4*)(Wcat + (size_t)o * 512 + cc);
        ushort4 ov;
        ov.x = f2bf(v.x); ov.y = f2bf(v.y); ov.z = f2bf(v.z); ov.w = f2bf(v.w);
        *(ushort4*)(Wcomb + (size_t)o * KTOT + cc) = ov;
    } else if (bid < 288) {
        int gid = (bid - 160) * 256 + tid;  // 0..32767
        float x = rxyz[gid * 3 + 0];
        float y = rxyz[gid * 3 + 1];
        float z = rxyz[gid * 3 + 2];
        float r2 = __fadd_rn(__fadd_rn(__fmul_rn(x, x), __fmul_rn(y, y)), __fmul_rn(z, z));
        refpk[gid] = make_float4(x, y, z, r2);
    } else {
        // ---- seedT: transpose+convert seed (B,CS,S) fp32 -> (B,S,CS) bf16 ----
        // Same f2bf values the gemm previously computed inline -> bit-identical.
        int id = bid - 288;                // 0..1023
        int b = id >> 8;
        int rem = id & 255;
        int c0 = (rem >> 6) * 64;          // 0..192
        int s0 = (rem & 63) * 64;          // 0..4032
        int tx = tid & 15, ty = tid >> 4;
        #pragma unroll
        for (int r = 0; r < 4; ++r) {
            int cc = r * 16 + ty;
            float4 v = *(const float4*)(seed + ((size_t)b * CS + c0 + cc) * S_ + s0 + tx * 4);
            sa[tx * 4 + 0][cc] = v.x;
            sa[tx * 4 + 1][cc] = v.y;
            sa[tx * 4 + 2][cc] = v.z;
            sa[tx * 4 + 3][cc] = v.w;
        }
        __syncthreads();
        #pragma unroll
        for (int r = 0; r < 4; ++r) {
            int n = r * 16 + ty;
            ushort4 o;
            o.x = f2bf(sa[n][tx * 4 + 0]);
            o.y = f2bf(sa[n][tx * 4 + 1]);
            o.z = f2bf(sa[n][tx * 4 + 2]);
            o.w = f2bf(sa[n][tx * 4 + 3]);
            *(ushort4*)(seedT + ((size_t)b * S_ + s0 + n) * CS + c0 + tx * 4) = o;
        }
    }
}

// ================= K2: fused argmin + transpose (R3 verbatim, proven 56.4us) =================
// 6144 blocks, 1:2 argmin:transpose interleave.
__global__ __launch_bounds__(256, 4) void mid_kernel(
        const float* __restrict__ qxyz, const float4* __restrict__ refpk,
        float* __restrict__ pval, int* __restrict__ pidx,
        const float* __restrict__ rf, unsigned short* __restrict__ refT) {
    __shared__ float t[64][65];
    int bid = blockIdx.x;
    int tid = threadIdx.x;

    if (bid % 3 != 0) {
        // ---------- transpose path: (B,C,Nc) fp32 -> (B,Nc,C) bf16 ----------
        int id = bid - bid / 3 - 1;        // 0..4095
        int b = id >> 10;
        int c0 = ((id >> 7) & 7) * 64;
        int n0 = (id & 127) * 64;
        int tx = tid & 15, ty = tid >> 4;
        #pragma unroll
        for (int r = 0; r < 4; ++r) {
            int cc = r * 16 + ty;
            float4 v = *(const float4*)(rf + ((size_t)b * C_ + c0 + cc) * NC + n0 + tx * 4);
            t[tx * 4 + 0][cc] = v.x;
            t[tx * 4 + 1][cc] = v.y;
            t[tx * 4 + 2][cc] = v.z;
            t[tx * 4 + 3][cc] = v.w;
        }
        __syncthreads();
        #pragma unroll
        for (int r = 0; r < 4; ++r) {
            int n = r * 16 + ty;
            ushort4 o;
            o.x = f2bf(t[n][tx * 4 + 0]);
            o.y = f2bf(t[n][tx * 4 + 1]);
            o.z = f2bf(t[n][tx * 4 + 2]);
            o.w = f2bf(t[n][tx * 4 + 3]);
            *(ushort4*)(refT + ((size_t)b * NC + n0 + n) * C_ + c0 + tx * 4) = o;
        }
    } else {
        // ---------- argmin path: one 2048-ref chunk, 32 queries/block ----------
        int aid = bid / 3;                 // 0..2047
        int sblk = aid & 127;
        int c = (aid >> 7) & 3;
        int b = aid >> 9;
        int lane = tid & 63;
        int qg = tid >> 6;
        int sbase = sblk * 32 + qg * 8;

        float qx[8], qy[8], qz[8], q2[8];
        #pragma unroll
        for (int q = 0; q < 8; ++q) {
            const float* qp = qxyz + ((size_t)(b * S_ + sbase + q)) * 3;
            qx[q] = qp[0]; qy[q] = qp[1]; qz[q] = qp[2];
            q2[q] = __fadd_rn(__fadd_rn(__fmul_rn(qx[q], qx[q]), __fmul_rn(qy[q], qy[q])),
                              __fmul_rn(qz[q], qz[q]));
        }

        const float4* ep = refpk + (size_t)b * NC + c * 2048 + lane;
        float best[8];
        int bj[8];
        #pragma unroll
        for (int q = 0; q < 8; ++q) { best[q] = 3.4028235e38f; bj[q] = 0; }

        // 2-deep software prefetch; processing order stays ascending.
        float4 r0 = ep[0];
        float4 r1 = ep[64];
        #pragma unroll 2
        for (int j = 0; j < 32; j += 2) {
            float4 r2 = r0, r3 = r1;
            if (j + 2 < 32) {
                r2 = ep[(j + 2) * 64];
                r3 = ep[(j + 3) * 64];
            }
            #pragma unroll
            for (int q = 0; q < 8; ++q) {
                // qr = ((qx*rx + qy*ry) + qz*rz), no FMA (np association)
                float qr = __fadd_rn(__fadd_rn(__fmul_rn(qx[q], r0.x), __fmul_rn(qy[q], r0.y)),
                                     __fmul_rn(qz[q], r0.z));
                float s = __fadd_rn(q2[q], r0.w);
                float d2 = fmaf(qr, -2.0f, s);   // same single rounding as fsub(s, qr+qr)
                if (d2 < best[q]) { best[q] = d2; bj[q] = j; }
            }
            #pragma unroll
            for (int q = 0; q < 8; ++q) {
                float qr = __fadd_rn(__fadd_rn(__fmul_rn(qx[q], r1.x), __fmul_rn(qy[q], r1.y)),
                                     __fmul_rn(qz[q], r1.z));
                float s = __fadd_rn(q2[q], r1.w);
                float d2 = fmaf(qr, -2.0f, s);
                if (d2 < best[q]) { best[q] = d2; bj[q] = j + 1; }
            }
            r0 = r2;
            r1 = r3;
        }

        int bx[8];
        #pragma unroll
        for (int q = 0; q < 8; ++q) bx[q] = c * 2048 + bj[q] * 64 + lane;

        // In-wave butterfly, (val, idx) lexicographic min = first occurrence.
        #pragma unroll
        for (int m = 1; m < 64; m <<= 1) {
            #pragma unroll
            for (int q = 0; q < 8; ++q) {
                float vv = __shfl_xor(best[q], m, 64);
                int xx = __shfl_xor(bx[q], m, 64);
                if (vv < best[q] || (vv == best[q] && xx < bx[q])) {
                    best[q] = vv; bx[q] = xx;
                }
            }
        }
        if (lane == 0) {
            #pragma unroll
            for (int q = 0; q < 8; ++q) {
                int qs = b * S_ + sbase + q;
                pval[qs * 4 + c] = best[q];
                pidx[qs * 4 + c] = bx[q];
            }
        }
    }
}

// ================= K3: fused merge + gather + GEMM, retiled =================
// out[b](256 x 4096) = Wcomb(256x768) @ [seedT^T; gathered refT^T] + b_eff
// BM=64, BN=64, BK=64, 256 threads (2x2 waves of 32x32), single-buffer LDS
// 18.4KB -> 8 blocks/CU residency, grid (64,4,4)=1024. Both B halves are
// uniform contiguous bf16 row reads (seedT rows / gathered refT rows):
// no f2bf and no strided fp32 chain in the hot loop. MFMA K-accumulation
// order per output element unchanged (ks then kf) -> bit-identical.
__global__ __launch_bounds__(256) void fused_gemm_kernel(
        const unsigned short* __restrict__ Wcomb,
        const unsigned short* __restrict__ seedT,
        const unsigned short* __restrict__ refT,
        const float* __restrict__ pval,
        const int* __restrict__ pidx,
        const float* __restrict__ beff,
        float* __restrict__ out) {
    __shared__ __align__(16) unsigned short sA[64][72];
    __shared__ __align__(16) unsigned short sB[64][72];
    __shared__ int sIdx[64];
    __shared__ float sBias[64];

    int tid = threadIdx.x;
    int b = blockIdx.z;
    int m0 = blockIdx.y * 64;
    int s0 = blockIdx.x * 64;
    if (tid < 64) {
        // merge 4 chunk-partials; disjoint ascending index ranges -> (val,idx) min
        int qs = b * S_ + s0 + tid;
        float v = pval[qs * 4 + 0];
        int x = pidx[qs * 4 + 0];
        #pragma unroll
        for (int c = 1; c < 4; ++c) {
            float vv = pval[qs * 4 + c];
            int xx = pidx[qs * 4 + c];
            if (vv < v || (vv == v && xx < x)) { v = vv; x = xx; }
        }
        sIdx[tid] = x & (NC - 1);   // defensive clamp
        sBias[tid] = beff[m0 + tid];
    }

    int lane = tid & 63;
    int w = tid >> 6;
    int wm = w >> 1;                // 0..1
    int wn = w & 1;                 // 0..1
    int ln = lane & 15;
    int quad = lane >> 4;
    int q8 = quad * 8;

    int mm   = tid >> 2;            // A/B row 0..63
    int kk16 = (tid & 3) << 4;      // k offset in tile {0,16,32,48}
    const unsigned short* Arow = Wcomb + (size_t)(m0 + mm) * KTOT + kk16;
    const unsigned short* Srow = seedT + ((size_t)b * S_ + s0 + mm) * CS + kk16;

    f32x4 acc[2][2];
    #pragma unroll
    for (int i = 0; i < 2; ++i)
        #pragma unroll
        for (int j = 0; j < 2; ++j)
            acc[i][j] = (f32x4){0.f, 0.f, 0.f, 0.f};

    for (int ks = 0; ks < 12; ++ks) {
        int k0 = ks * 64;
        __syncthreads();            // (for ks=0 this also covers the sIdx write)
        *(short8*)&sA[mm][kk16]     = *(const short8*)(Arow + k0);
        *(short8*)&sA[mm][kk16 + 8] = *(const short8*)(Arow + k0 + 8);
        const unsigned short* Brow =
            (k0 < 256) ? (Srow + k0)
                       : (refT + ((size_t)b * NC + sIdx[mm]) * C_ + (k0 - 256) + kk16);
        *(short8*)&sB[mm][kk16]     = *(const short8*)(Brow);
        *(short8*)&sB[mm][kk16 + 8] = *(const short8*)(Brow + 8);
        __syncthreads();
        #pragma unroll
        for (int kf = 0; kf < 2; ++kf) {
            short8 af[2], bfr[2];
            #pragma unroll
            for (int i = 0; i < 2; ++i)
                af[i] = *(const short8*)&sA[wm * 32 + i * 16 + ln][kf * 32 + q8];
            #pragma unroll
            for (int j = 0; j < 2; ++j)
                bfr[j] = *(const short8*)&sB[wn * 32 + j * 16 + ln][kf * 32 + q8];
            #pragma unroll
            for (int i = 0; i < 2; ++i)
                #pragma unroll
                for (int j = 0; j < 2; ++j)
                    acc[i][j] = __builtin_amdgcn_mfma_f32_16x16x32_bf16(af[i], bfr[j], acc[i][j], 0, 0, 0);
        }
    }

    #pragma unroll
    for (int i = 0; i < 2; ++i) {
        int mb = wm * 32 + i * 16 + quad * 4;
        #pragma unroll
        for (int j = 0; j < 2; ++j) {
            int col = s0 + wn * 32 + j * 16 + ln;
            #pragma unroll
            for (int r = 0; r < 4; ++r) {
                int m = mb + r;
                out[((size_t)b * CS + m0 + m) * S_ + col] = acc[i][j][r] + sBias[m];
            }
        }
    }
}

extern "C" void kernel_launch(void* const* d_in, const int* in_sizes, int n_in,
                              void* d_out, int out_size, void* d_ws, size_t ws_size,
                              hipStream_t stream) {
    const float* qxyz  = (const float*)d_in[0];
    const float* rxyz  = (const float*)d_in[1];
    const float* rfeat = (const float*)d_in[2];
    const float* seed  = (const float*)d_in[3];
    const float* Wseed = (const float*)d_in[4];
    const float* bseed = (const float*)d_in[5];
    const float* Wcat  = (const float*)d_in[6];
    const float* bcat  = (const float*)d_in[7];
    float* out = (float*)d_out;

    char* ws = (char*)d_ws;
    float* pval           = (float*)(ws);                        // 256 KB
    int* pidx             = (int*)(ws + 262144);                 // 256 KB
    float* beff           = (float*)(ws + 524288);               // 1 KB
    float4* refpk         = (float4*)(ws + 528384);              // 512 KB
    unsigned short* Wcomb = (unsigned short*)(ws + 1052672);     // 384 KB
    unsigned short* refT  = (unsigned short*)(ws + 1445888);     // 32 MB -> 35000320
    unsigned short* seedT = (unsigned short*)(ws + 35000320);    // 8 MB  -> end 43.4 MB

    hipLaunchKernelGGL(prep_kernel, dim3(1312), dim3(256), 0, stream,
                       rxyz, refpk, Wcat, Wseed, Wcomb, bseed, bcat, beff, seed, seedT);
    hipLaunchKernelGGL(mid_kernel, dim3(6144), dim3(256), 0, stream,
                       qxyz, refpk, pval, pidx, rfeat, refT);
    hipLaunchKernelGGL(fused_gemm_kernel, dim3(64, 4, 4), dim3(256), 0, stream,
                       Wcomb, seedT, refT, pval, pidx, beff, out);
}

// Round 8
// 181.912 us; speedup vs baseline: 1.3848x; 1.0076x over previous
//
#include <hip/hip_runtime.h>

#define B_   4
#define S_   4096
#define NC   8192
#define C_   512
#define CS   256
#define KTOT 768

typedef __attribute__((ext_vector_type(8))) short short8;
typedef __attribute__((ext_vector_type(4))) float f32x4;

// fp32 -> bf16 round-to-nearest-even (finite inputs only)
static __device__ __forceinline__ unsigned short f2bf(float x) {
    unsigned u = __builtin_bit_cast(unsigned, x);
    unsigned r = u + 0x7FFFu + ((u >> 16) & 1u);
    return (unsigned short)(r >> 16);
}

// ================= K1: fused prep (R3 verbatim, 288 blocks) =================
// bid 0..63: beff | 64..95: wc | 96..159: w1 | 160..287: pad_ref
__global__ __launch_bounds__(256) void prep_kernel(
        const float* __restrict__ rxyz, float4* __restrict__ refpk,
        const float* __restrict__ Wcat, const float* __restrict__ Wseed,
        unsigned short* __restrict__ Wcomb,
        const float* __restrict__ bseed, const float* __restrict__ bcat,
        float* __restrict__ beff) {
    __shared__ float sa[64][68];
    __shared__ float sbt[64][68];
    int bid = blockIdx.x;
    int tid = threadIdx.x;

    if (bid < 64) {
        int w = tid >> 6, l = tid & 63;
        int o = bid * 4 + w;
        float4 wv = *(const float4*)(Wcat + (size_t)o * 512 + 256 + l * 4);
        float4 bb = *(const float4*)(bseed + l * 4);
        float acc = __fmul_rn(wv.x, bb.x);
        acc = fmaf(wv.y, bb.y, acc);
        acc = fmaf(wv.z, bb.z, acc);
        acc = fmaf(wv.w, bb.w, acc);
        #pragma unroll
        for (int off = 32; off > 0; off >>= 1) acc += __shfl_down(acc, off);
        if (l == 0) beff[o] = acc + bcat[o];
    } else if (bid < 96) {
        int xb = bid - 64;
        int tc = (xb & 7) * 64;
        int to = (xb >> 3) * 64;
        int tx = tid & 15, ty = tid >> 4;
        float acc[4][4] = {};
        for (int kt = 0; kt < 256; kt += 64) {
            __syncthreads();
            #pragma unroll
            for (int r = 0; r < 4; ++r) {
                int oo = r * 16 + ty;
                float4 v = *(const float4*)(Wcat + (size_t)(to + oo) * 512 + 256 + kt + tx * 4);
                sa[oo][tx * 4 + 0] = v.x;
                sa[oo][tx * 4 + 1] = v.y;
                sa[oo][tx * 4 + 2] = v.z;
                sa[oo][tx * 4 + 3] = v.w;
                float4 u = *(const float4*)(Wseed + (size_t)(kt + oo) * 512 + tc + tx * 4);
                sbt[oo][tx * 4 + 0] = u.x;
                sbt[oo][tx * 4 + 1] = u.y;
                sbt[oo][tx * 4 + 2] = u.z;
                sbt[oo][tx * 4 + 3] = u.w;
            }
            __syncthreads();
            for (int k = 0; k < 64; ++k) {
                float a[4], bb2[4];
                #pragma unroll
                for (int i = 0; i < 4; ++i) a[i] = sa[ty * 4 + i][k];
                #pragma unroll
                for (int j = 0; j < 4; ++j) bb2[j] = sbt[k][tx * 4 + j];
                #pragma unroll
                for (int i = 0; i < 4; ++i)
                    #pragma unroll
                    for (int j = 0; j < 4; ++j)
                        acc[i][j] = fmaf(a[i], bb2[j], acc[i][j]);
            }
        }
        #pragma unroll
        for (int i = 0; i < 4; ++i)
            #pragma unroll
            for (int j = 0; j < 4; ++j)
                Wcomb[(size_t)(to + ty * 4 + i) * KTOT + 256 + tc + tx * 4 + j] = f2bf(acc[i][j]);
    } else if (bid < 160) {
        int g = ((bid - 96) * 256 + tid) * 4;
        int o = g >> 8, cc = g & 255;
        float4 v = *(const float4*)(Wcat + (size_t)o * 512 + cc);
        ushort4 ov;
        ov.x = f2bf(v.x); ov.y = f2bf(v.y); ov.z = f2bf(v.z); ov.w = f2bf(v.w);
        *(ushort4*)(Wcomb + (size_t)o * KTOT + cc) = ov;
    } else {
        int gid = (bid - 160) * 256 + tid;  // 0..32767
        float x = rxyz[gid * 3 + 0];
        float y = rxyz[gid * 3 + 1];
        float z = rxyz[gid * 3 + 2];
        float r2 = __fadd_rn(__fadd_rn(__fmul_rn(x, x), __fmul_rn(y, y)), __fmul_rn(z, z));
        refpk[gid] = make_float4(x, y, z, r2);
    }
}

// ================= K2: fused argmin + refT transpose + seedT transpose =================
// 7168 blocks, residue mod 7: {0,4} -> argmin (2048, R3-proven verbatim),
// {1,2,3,5} -> refT transpose (4096, verbatim), {6} -> seedT transpose
// (1024, moved from prep: pure-HBM work rides argmin's idle memory pipe;
// mid HBM timeline ~120MB ~19us << 56us VALU timeline -> hidden).
__global__ __launch_bounds__(256, 4) void mid_kernel(
        const float* __restrict__ qxyz, const float4* __restrict__ refpk,
        float* __restrict__ pval, int* __restrict__ pidx,
        const float* __restrict__ rf, unsigned short* __restrict__ refT,
        const float* __restrict__ seed, unsigned short* __restrict__ seedT) {
    __shared__ float t[64][65];
    int bid = blockIdx.x;
    int tid = threadIdx.x;
    int r7 = bid % 7;
    int g7 = bid / 7;                      // 0..1023

    if (r7 == 0 || r7 == 4) {
        // ---------- argmin path: one 2048-ref chunk, 32 queries/block ----------
        int aid = g7 * 2 + (r7 == 4);      // 0..2047
        int sblk = aid & 127;
        int c = (aid >> 7) & 3;
        int b = aid >> 9;
        int lane = tid & 63;
        int qg = tid >> 6;
        int sbase = sblk * 32 + qg * 8;

        float qx[8], qy[8], qz[8], q2[8];
        #pragma unroll
        for (int q = 0; q < 8; ++q) {
            const float* qp = qxyz + ((size_t)(b * S_ + sbase + q)) * 3;
            qx[q] = qp[0]; qy[q] = qp[1]; qz[q] = qp[2];
            q2[q] = __fadd_rn(__fadd_rn(__fmul_rn(qx[q], qx[q]), __fmul_rn(qy[q], qy[q])),
                              __fmul_rn(qz[q], qz[q]));
        }

        const float4* ep = refpk + (size_t)b * NC + c * 2048 + lane;
        float best[8];
        int bj[8];
        #pragma unroll
        for (int q = 0; q < 8; ++q) { best[q] = 3.4028235e38f; bj[q] = 0; }

        // 2-deep software prefetch; processing order stays ascending.
        float4 r0 = ep[0];
        float4 r1 = ep[64];
        #pragma unroll 2
        for (int j = 0; j < 32; j += 2) {
            float4 r2 = r0, r3 = r1;
            if (j + 2 < 32) {
                r2 = ep[(j + 2) * 64];
                r3 = ep[(j + 3) * 64];
            }
            #pragma unroll
            for (int q = 0; q < 8; ++q) {
                // qr = ((qx*rx + qy*ry) + qz*rz), no FMA (np association)
                float qr = __fadd_rn(__fadd_rn(__fmul_rn(qx[q], r0.x), __fmul_rn(qy[q], r0.y)),
                                     __fmul_rn(qz[q], r0.z));
                float s = __fadd_rn(q2[q], r0.w);
                float d2 = fmaf(qr, -2.0f, s);   // same single rounding as fsub(s, qr+qr)
                if (d2 < best[q]) { best[q] = d2; bj[q] = j; }
            }
            #pragma unroll
            for (int q = 0; q < 8; ++q) {
                float qr = __fadd_rn(__fadd_rn(__fmul_rn(qx[q], r1.x), __fmul_rn(qy[q], r1.y)),
                                     __fmul_rn(qz[q], r1.z));
                float s = __fadd_rn(q2[q], r1.w);
                float d2 = fmaf(qr, -2.0f, s);
                if (d2 < best[q]) { best[q] = d2; bj[q] = j + 1; }
            }
            r0 = r2;
            r1 = r3;
        }

        int bx[8];
        #pragma unroll
        for (int q = 0; q < 8; ++q) bx[q] = c * 2048 + bj[q] * 64 + lane;

        // In-wave butterfly, (val, idx) lexicographic min = first occurrence.
        #pragma unroll
        for (int m = 1; m < 64; m <<= 1) {
            #pragma unroll
            for (int q = 0; q < 8; ++q) {
                float vv = __shfl_xor(best[q], m, 64);
                int xx = __shfl_xor(bx[q], m, 64);
                if (vv < best[q] || (vv == best[q] && xx < bx[q])) {
                    best[q] = vv; bx[q] = xx;
                }
            }
        }
        if (lane == 0) {
            #pragma unroll
            for (int q = 0; q < 8; ++q) {
                int qs = b * S_ + sbase + q;
                pval[qs * 4 + c] = best[q];
                pidx[qs * 4 + c] = bx[q];
            }
        }
    } else if (r7 != 6) {
        // ---------- refT transpose: (B,C,Nc) fp32 -> (B,Nc,C) bf16 ----------
        int id = g7 * 4 + (r7 - 1 - (r7 > 4 ? 1 : 0));   // 0..4095
        int b = id >> 10;
        int c0 = ((id >> 7) & 7) * 64;
        int n0 = (id & 127) * 64;
        int tx = tid & 15, ty = tid >> 4;
        #pragma unroll
        for (int r = 0; r < 4; ++r) {
            int cc = r * 16 + ty;
            float4 v = *(const float4*)(rf + ((size_t)b * C_ + c0 + cc) * NC + n0 + tx * 4);
            t[tx * 4 + 0][cc] = v.x;
            t[tx * 4 + 1][cc] = v.y;
            t[tx * 4 + 2][cc] = v.z;
            t[tx * 4 + 3][cc] = v.w;
        }
        __syncthreads();
        #pragma unroll
        for (int r = 0; r < 4; ++r) {
            int n = r * 16 + ty;
            ushort4 o;
            o.x = f2bf(t[n][tx * 4 + 0]);
            o.y = f2bf(t[n][tx * 4 + 1]);
            o.z = f2bf(t[n][tx * 4 + 2]);
            o.w = f2bf(t[n][tx * 4 + 3]);
            *(ushort4*)(refT + ((size_t)b * NC + n0 + n) * C_ + c0 + tx * 4) = o;
        }
    } else {
        // ---------- seedT transpose: (B,CS,S) fp32 -> (B,S,CS) bf16 ----------
        // Same f2bf values as the prep-resident version -> bit-identical.
        int id = g7;                       // 0..1023
        int b = id >> 8;
        int rem = id & 255;
        int c0 = (rem >> 6) * 64;          // 0..192
        int s0 = (rem & 63) * 64;          // 0..4032
        int tx = tid & 15, ty = tid >> 4;
        #pragma unroll
        for (int r = 0; r < 4; ++r) {
            int cc = r * 16 + ty;
            float4 v = *(const float4*)(seed + ((size_t)b * CS + c0 + cc) * S_ + s0 + tx * 4);
            t[tx * 4 + 0][cc] = v.x;
            t[tx * 4 + 1][cc] = v.y;
            t[tx * 4 + 2][cc] = v.z;
            t[tx * 4 + 3][cc] = v.w;
        }
        __syncthreads();
        #pragma unroll
        for (int r = 0; r < 4; ++r) {
            int n = r * 16 + ty;
            ushort4 o;
            o.x = f2bf(t[n][tx * 4 + 0]);
            o.y = f2bf(t[n][tx * 4 + 1]);
            o.z = f2bf(t[n][tx * 4 + 2]);
            o.w = f2bf(t[n][tx * 4 + 3]);
            *(ushort4*)(seedT + ((size_t)b * S_ + s0 + n) * CS + c0 + tx * 4) = o;
        }
    }
}

// ================= K3: fused merge + gather + GEMM, retiled + 2-phase =================
// out[b](256 x 4096) = Wcomb(256x768) @ [seedT^T; gathered refT^T] + b_eff
// R7 tile (BM=64, BN=64, BK=64, 2x2 waves) + double-buffered LDS with
// register prefetch: SLOAD(ks+1) issues BEFORE the MFMA of ks, hiding the
// random refT-row latency (R7 single-buffer exposed it 12x/block).
// One barrier per step. MFMA K-order unchanged (ks then kf) -> bit-identical.
// LDS 36.9KB -> 4 blocks/CU; grid 1024 = all resident.
__global__ __launch_bounds__(256) void fused_gemm_kernel(
        const unsigned short* __restrict__ Wcomb,
        const unsigned short* __restrict__ seedT,
        const unsigned short* __restrict__ refT,
        const float* __restrict__ pval,
        const int* __restrict__ pidx,
        const float* __restrict__ beff,
        float* __restrict__ out) {
    __shared__ __align__(16) unsigned short sA[2][64][72];
    __shared__ __align__(16) unsigned short sB[2][64][72];
    __shared__ int sIdx[64];
    __shared__ float sBias[64];

    int tid = threadIdx.x;
    int b = blockIdx.z;
    int m0 = blockIdx.y * 64;
    int s0 = blockIdx.x * 64;
    if (tid < 64) {
        // merge 4 chunk-partials; disjoint ascending index ranges -> (val,idx) min
        int qs = b * S_ + s0 + tid;
        float v = pval[qs * 4 + 0];
        int x = pidx[qs * 4 + 0];
        #pragma unroll
        for (int c = 1; c < 4; ++c) {
            float vv = pval[qs * 4 + c];
            int xx = pidx[qs * 4 + c];
            if (vv < v || (vv == v && xx < x)) { v = vv; x = xx; }
        }
        sIdx[tid] = x & (NC - 1);   // defensive clamp
        sBias[tid] = beff[m0 + tid];
    }

    int lane = tid & 63;
    int w = tid >> 6;
    int wm = w >> 1;                // 0..1
    int wn = w & 1;                 // 0..1
    int ln = lane & 15;
    int quad = lane >> 4;
    int q8 = quad * 8;

    int mm   = tid >> 2;            // A/B row 0..63
    int kk16 = (tid & 3) << 4;      // k offset in tile {0,16,32,48}
    const unsigned short* Arow = Wcomb + (size_t)(m0 + mm) * KTOT + kk16;
    const unsigned short* Srow = seedT + ((size_t)b * S_ + s0 + mm) * CS + kk16;

    f32x4 acc[2][2];
    #pragma unroll
    for (int i = 0; i < 2; ++i)
        #pragma unroll
        for (int j = 0; j < 2; ++j)
            acc[i][j] = (f32x4){0.f, 0.f, 0.f, 0.f};

    short8 ra0, ra1, rb0, rb1;

    // NOTE: sIdx is first read by SLOAD(4) (issued in iter ks=3), which is
    // after the prologue barrier -> ordering safe.
    #define SLOAD(PK) do {                                                         \
        int pk0 = (PK) * 64;                                                       \
        ra0 = *(const short8*)(Arow + pk0);                                        \
        ra1 = *(const short8*)(Arow + pk0 + 8);                                    \
        const unsigned short* Brow =                                               \
            (pk0 < 256) ? (Srow + pk0)                                             \
                        : (refT + ((size_t)b * NC + sIdx[mm]) * C_                 \
                           + (pk0 - 256) + kk16);                                  \
        rb0 = *(const short8*)(Brow);                                              \
        rb1 = *(const short8*)(Brow + 8);                                          \
    } while (0)

    #define SWRITE(BUF) do {                                                       \
        *(short8*)&sA[BUF][mm][kk16]     = ra0;                                    \
        *(short8*)&sA[BUF][mm][kk16 + 8] = ra1;                                    \
        *(short8*)&sB[BUF][mm][kk16]     = rb0;                                    \
        *(short8*)&sB[BUF][mm][kk16 + 8] = rb1;                                    \
    } while (0)

    SLOAD(0);
    SWRITE(0);
    __syncthreads();                // also covers sIdx/sBias writes

    int cur = 0;
    for (int ks = 0; ks < 12; ++ks) {
        if (ks < 11) SLOAD(ks + 1);     // prefetch next tile: hides under MFMA
        #pragma unroll
        for (int kf = 0; kf < 2; ++kf) {
            short8 af[2], bfr[2];
            #pragma unroll
            for (int i = 0; i < 2; ++i)
                af[i] = *(const short8*)&sA[cur][wm * 32 + i * 16 + ln][kf * 32 + q8];
            #pragma unroll
            for (int j = 0; j < 2; ++j)
                bfr[j] = *(const short8*)&sB[cur][wn * 32 + j * 16 + ln][kf * 32 + q8];
            #pragma unroll
            for (int i = 0; i < 2; ++i)
                #pragma unroll
                for (int j = 0; j < 2; ++j)
                    acc[i][j] = __builtin_amdgcn_mfma_f32_16x16x32_bf16(af[i], bfr[j], acc[i][j], 0, 0, 0);
        }
        if (ks < 11) {
            SWRITE(cur ^ 1);            // other buffer: no reader until after barrier
            __syncthreads();            // ONE barrier per K-step
            cur ^= 1;
        }
    }
    #undef SLOAD
    #undef SWRITE

    #pragma unroll
    for (int i = 0; i < 2; ++i) {
        int mb = wm * 32 + i * 16 + quad * 4;
        #pragma unroll
        for (int j = 0; j < 2; ++j) {
            int col = s0 + wn * 32 + j * 16 + ln;
            #pragma unroll
            for (int r = 0; r < 4; ++r) {
                int m = mb + r;
                out[((size_t)b * CS + m0 + m) * S_ + col] = acc[i][j][r] + sBias[m];
            }
        }
    }
}

extern "C" void kernel_launch(void* const* d_in, const int* in_sizes, int n_in,
                              void* d_out, int out_size, void* d_ws, size_t ws_size,
                              hipStream_t stream) {
    const float* qxyz  = (const float*)d_in[0];
    const float* rxyz  = (const float*)d_in[1];
    const float* rfeat = (const float*)d_in[2];
    const float* seed  = (const float*)d_in[3];
    const float* Wseed = (const float*)d_in[4];
    const float* bseed = (const float*)d_in[5];
    const float* Wcat  = (const float*)d_in[6];
    const float* bcat  = (const float*)d_in[7];
    float* out = (float*)d_out;

    char* ws = (char*)d_ws;
    float* pval           = (float*)(ws);                        // 256 KB
    int* pidx             = (int*)(ws + 262144);                 // 256 KB
    float* beff           = (float*)(ws + 524288);               // 1 KB
    float4* refpk         = (float4*)(ws + 528384);              // 512 KB
    unsigned short* Wcomb = (unsigned short*)(ws + 1052672);     // 384 KB
    unsigned short* refT  = (unsigned short*)(ws + 1445888);     // 32 MB -> 35000320
    unsigned short* seedT = (unsigned short*)(ws + 35000320);    // 8 MB  -> end 43.4 MB

    hipLaunchKernelGGL(prep_kernel, dim3(288), dim3(256), 0, stream,
                       rxyz, refpk, Wcat, Wseed, Wcomb, bseed, bcat, beff);
    hipLaunchKernelGGL(mid_kernel, dim3(7168), dim3(256), 0, stream,
                       qxyz, refpk, pval, pidx, rfeat, refT, seed, seedT);
    hipLaunchKernelGGL(fused_gemm_kernel, dim3(64, 4, 4), dim3(256), 0, stream,
                       Wcomb, seedT, refT, pval, pidx, beff, out);
}